// Round 9
// baseline (507.236 us; speedup 1.0000x reference)
//
#include <hip/hip_runtime.h>
#include <hip/hip_bf16.h>

#define NREL 3
#define EMB 32
#define HID 64

typedef __attribute__((ext_vector_type(8))) short short8_t;
typedef __attribute__((ext_vector_type(4))) short short4_t;
typedef __attribute__((ext_vector_type(4))) float f32x4;

__device__ inline short f2bf(float v) {
  __hip_bfloat16 b = __float2bfloat16(v);
  short s;
  __builtin_memcpy(&s, &b, 2);
  return s;
}
__device__ inline float bf2f(short s) {
  __hip_bfloat16 b;
  __builtin_memcpy(&b, &s, 2);
  return __bfloat162float(b);
}
__device__ inline void split8(const float* v, short8_t* h, short8_t* l) {
#pragma unroll
  for (int i = 0; i < 8; i++) {
    short hh = f2bf(v[i]);
    (*h)[i] = hh;
    (*l)[i] = f2bf(v[i] - bf2f(hh));
  }
}

// ---- fused prep: embedding + FUSED edge histogram+nbr-scatter + weight prep ----
// The histogram atomicAdd's return value IS the CSR slot: write nbr[idx*4+j] directly
// for j<4; append rare overflow (j>=4, ~1.2% of edges) to a compact list.
__global__ __launch_bounds__(256) void prep_k(
    const int* __restrict__ sid, const int* __restrict__ cid, const int* __restrict__ pid,
    const float* __restrict__ se, const float* __restrict__ ce, const float* __restrict__ pe,
    short* __restrict__ xh, short* __restrict__ xl,
    const int* __restrict__ src, const int* __restrict__ dst, const int* __restrict__ et,
    int* __restrict__ icnt, int* __restrict__ nbr,
    int* __restrict__ ovf_idx, int* __restrict__ ovf_src, int* __restrict__ ovfn,
    const float* __restrict__ root1, const float* __restrict__ W1,
    const float* __restrict__ root2, const float* __restrict__ W2,
    short* __restrict__ w1h, short* __restrict__ w1l,
    short* __restrict__ w2h, short* __restrict__ w2l, int N, int E) {
  int i = blockIdx.x * 256 + threadIdx.x;
  if (i < N * 8) {  // embedding: one float4 slice per thread
    int n = i >> 3, cg = i & 7;
    const float4 a = *(const float4*)&se[sid[n] * EMB + cg * 4];
    const float4 b = *(const float4*)&ce[cid[n] * EMB + cg * 4];
    const float4 c = *(const float4*)&pe[pid[n] * EMB + cg * 4];
    float v[4];
    v[0] = a.x + b.x + c.x; v[1] = a.y + b.y + c.y;
    v[2] = a.z + b.z + c.z; v[3] = a.w + b.w + c.w;
    short4_t h, l;
#pragma unroll
    for (int j = 0; j < 4; j++) {
      short hh = f2bf(v[j]);
      h[j] = hh;
      l[j] = f2bf(v[j] - bf2f(hh));
    }
    *(short4_t*)&xh[(size_t)n * EMB + cg * 4] = h;
    *(short4_t*)&xl[(size_t)n * EMB + cg * 4] = l;
  }
  if (i < E) {  // fused histogram + first-4 scatter + overflow append
    int idx = et[i] * N + dst[i];
    int j = atomicAdd(&icnt[idx], 1);
    int s = src[i];
    if (j < 4) {
      nbr[(size_t)idx * 4 + j] = s;
    } else {
      int p = atomicAdd(ovfn, 1);
      ovf_idx[p] = idx;
      ovf_src[p] = s;
    }
  }
  if (i < 64 * 128) {  // layer-1 weights
    int k = i >> 6, n = i & 63;
    float v = (k < EMB) ? root1[k * 64 + n] : W1[(k - EMB) * 64 + n];
    short h = f2bf(v);
    w1h[n * 128 + k] = h;
    w1l[n * 128 + k] = f2bf(v - bf2f(h));
  }
  if (i < 64 * 256) {  // layer-2 weights
    int k = i >> 6, n = i & 63;
    float v = (k < HID) ? root2[k * 64 + n] : W2[(k - HID) * 64 + n];
    short h = f2bf(v);
    w2h[n * 256 + k] = h;
    w2l[n * 256 + k] = f2bf(v - bf2f(h));
  }
}

// scans now prefix-sum the OVERFLOW lengths max(len-4,0) (csr holds only j>=4 slots)
__global__ __launch_bounds__(256) void scan1_k(const int* __restrict__ icnt,
                                               int* __restrict__ psum, int M) {
  int base = blockIdx.x * 1024 + threadIdx.x * 4;
  int s = 0;
#pragma unroll
  for (int j = 0; j < 4; j++) {
    int i = base + j;
    if (i < M) s += max(icnt[i] - 4, 0);
  }
  __shared__ int tmp[256];
  tmp[threadIdx.x] = s;
  __syncthreads();
  for (int off = 128; off > 0; off >>= 1) {
    if (threadIdx.x < off) tmp[threadIdx.x] += tmp[threadIdx.x + off];
    __syncthreads();
  }
  if (threadIdx.x == 0) psum[blockIdx.x] = tmp[0];
}

__global__ __launch_bounds__(256) void scan2_k(int* __restrict__ psum, int P) {
  __shared__ int tmp[256];
  __shared__ int carry_s;
  if (threadIdx.x == 0) carry_s = 0;
  __syncthreads();
  for (int base = 0; base < P; base += 256) {
    int i = base + threadIdx.x;
    int v = (i < P) ? psum[i] : 0;
    tmp[threadIdx.x] = v;
    __syncthreads();
    for (int off = 1; off < 256; off <<= 1) {
      int u = (threadIdx.x >= off) ? tmp[threadIdx.x - off] : 0;
      __syncthreads();
      tmp[threadIdx.x] += u;
      __syncthreads();
    }
    int carry = carry_s;
    if (i < P) psum[i] = carry + tmp[threadIdx.x] - v;
    __syncthreads();
    if (threadIdx.x == 0) carry_s = carry + tmp[255];
    __syncthreads();
  }
}

__global__ __launch_bounds__(256) void scan3_k(const int* __restrict__ icnt,
                                               const int* __restrict__ psum,
                                               int* __restrict__ offs, int M) {
  int base = blockIdx.x * 1024 + threadIdx.x * 4;
  int v[4];
  int s = 0;
#pragma unroll
  for (int j = 0; j < 4; j++) {
    int i = base + j;
    v[j] = (i < M) ? max(icnt[i] - 4, 0) : 0;
    s += v[j];
  }
  __shared__ int tmp[256];
  tmp[threadIdx.x] = s;
  __syncthreads();
  for (int off = 1; off < 256; off <<= 1) {
    int u = (threadIdx.x >= off) ? tmp[threadIdx.x - off] : 0;
    __syncthreads();
    tmp[threadIdx.x] += u;
    __syncthreads();
  }
  int run = psum[blockIdx.x] + tmp[threadIdx.x] - s;
#pragma unroll
  for (int j = 0; j < 4; j++) {
    int i = base + j;
    if (i < M) {
      offs[i] = run;
      run += v[j];
    }
  }
}

// tiny pass: place the ~18K overflow edges into the overflow CSR
__global__ __launch_bounds__(256) void ovfscatter_k(const int* __restrict__ ovf_idx,
                                                    const int* __restrict__ ovf_src,
                                                    const int* __restrict__ ovfn,
                                                    const int* __restrict__ offs,
                                                    int* __restrict__ cursor2,
                                                    int* __restrict__ csr) {
  int nn = *ovfn;
  for (int p = blockIdx.x * 256 + threadIdx.x; p < nn; p += gridDim.x * 256) {
    int idx = ovf_idx[p];
    int j2 = atomicAdd(&cursor2[idx], 1);
    csr[offs[idx] + j2] = ovf_src[p];
  }
}

// ====== layer-1 fused: barrier-phased LDS pipeline ======
__global__ __launch_bounds__(256) void l1fused_k(
    const short* __restrict__ xh, const short* __restrict__ xl,
    const int* __restrict__ offs, const int* __restrict__ icnt,
    const int* __restrict__ nbr, const int* __restrict__ csr,
    const short* __restrict__ wth, const short* __restrict__ wtl,
    const float* __restrict__ bias, short* __restrict__ h1h, short* __restrict__ h1l, int N) {
  __shared__ __align__(16) short lws[2][64][16][8];  // 32 KB
  __shared__ __align__(16) short gh_s[192][4][8];    // 12 KB
  __shared__ __align__(16) short gl_s[192][4][8];    // 12 KB
  __shared__ __align__(16) int4 mid_s[192];          //  3 KB
  __shared__ int mlen_s[192];
  __shared__ int mbeg_s[192];

  const int t = threadIdx.x;
  const int lane = t & 63, w = t >> 6;
  const int m_ = lane & 15, q = lane >> 4;
  const int n0b = blockIdx.x * 64;

  // ---- phase A ----
  int node_c = n0b + w * 16 + m_;
  if (node_c >= N) node_c = N - 1;
  short8_t ah0 = *(const short8_t*)&xh[(size_t)node_c * EMB + q * 8];
  short8_t al0 = *(const short8_t*)&xl[(size_t)node_c * EMB + q * 8];
#pragma unroll
  for (int i = 0; i < 8; i++) {
    int chi = t + 256 * i;
    int plane = chi >> 10;
    int rem = chi & 1023;
    int row = rem >> 4, c = rem & 15;
    const short* srcp = plane ? wtl : wth;
    short8_t wv = *(const short8_t*)&srcp[(size_t)row * 128 + c * 8];
    *(short8_t*)&lws[plane][row][c ^ (row & 7)][0] = wv;
  }
  if (t < 192) {
    int r = t >> 6, nl = t & 63;
    int n_ = n0b + nl;
    if (n_ >= N) n_ = N - 1;
    int idx = r * N + n_;
    mid_s[t] = *(const int4*)&nbr[(size_t)idx * 4];
    mlen_s[t] = icnt[idx];
    mbeg_s[t] = offs[idx];
  }
  __syncthreads();

  // ---- phase S: copy-shaped gather stage, 3 tasks/thread ----
  {
    int tslot[3], tq[3], tlen[3], tbeg[3];
    int4 tid4[3];
#pragma unroll
    for (int k = 0; k < 3; k++) {
      int tau = t + 256 * k;
      tslot[k] = tau >> 2;
      tq[k] = tau & 3;
      tid4[k] = mid_s[tslot[k]];
      tlen[k] = mlen_s[tslot[k]];
      tbeg[k] = mbeg_s[tslot[k]];
    }
    short8_t v0[3], v1[3], v2[3], v3[3];
#pragma unroll
    for (int k = 0; k < 3; k++) {
      int nself = n0b + (tslot[k] & 63);
      if (nself >= N) nself = N - 1;
      int g0 = (0 < tlen[k]) ? tid4[k].x : nself;
      int g1 = (1 < tlen[k]) ? tid4[k].y : nself;
      int g2 = (2 < tlen[k]) ? tid4[k].z : nself;
      int g3 = (3 < tlen[k]) ? tid4[k].w : nself;
      size_t co = (size_t)tq[k] * 8;
      v0[k] = *(const short8_t*)&xh[(size_t)g0 * EMB + co];
      v1[k] = *(const short8_t*)&xh[(size_t)g1 * EMB + co];
      v2[k] = *(const short8_t*)&xh[(size_t)g2 * EMB + co];
      v3[k] = *(const short8_t*)&xh[(size_t)g3 * EMB + co];
    }
#pragma unroll
    for (int k = 0; k < 3; k++) {
      float a[8];
      float k0 = (0 < tlen[k]) ? 1.f : 0.f;
      float k1 = (1 < tlen[k]) ? 1.f : 0.f;
      float k2 = (2 < tlen[k]) ? 1.f : 0.f;
      float k3 = (3 < tlen[k]) ? 1.f : 0.f;
#pragma unroll
      for (int i = 0; i < 8; i++)
        a[i] = k0 * bf2f(v0[k][i]) + k1 * bf2f(v1[k][i]) + k2 * bf2f(v2[k][i]) +
               k3 * bf2f(v3[k][i]);
      // rare tail: overflow CSR holds slots j>=4 at offs[idx] + (j-4)
      for (int j = 4; j < tlen[k]; j++) {
        short8_t u = *(const short8_t*)&xh[(size_t)csr[tbeg[k] + j - 4] * EMB + tq[k] * 8];
#pragma unroll
        for (int i = 0; i < 8; i++) a[i] += bf2f(u[i]);
      }
      float inv = 1.f / fmaxf((float)tlen[k], 1.f);
#pragma unroll
      for (int i = 0; i < 8; i++) a[i] *= inv;
      short8_t hi, lo;
      split8(a, &hi, &lo);
      int qs = tq[k] ^ (tslot[k] & 3);
      *(short8_t*)&gh_s[tslot[k]][qs][0] = hi;
      *(short8_t*)&gl_s[tslot[k]][qs][0] = lo;
    }
  }
  __syncthreads();

  // ---- phase C: pure LDS -> MFMA ----
  f32x4 acc[4];
#pragma unroll
  for (int i = 0; i < 4; i++) acc[i] = (f32x4){0.f, 0.f, 0.f, 0.f};
#pragma unroll
  for (int g = 0; g < 4; g++) {
    short8_t ah, al;
    if (g == 0) {
      ah = ah0;
      al = al0;
    } else {
      int slot = (g - 1) * 64 + w * 16 + m_;
      int qs = q ^ (slot & 3);
      ah = *(const short8_t*)&gh_s[slot][qs][0];
      al = *(const short8_t*)&gl_s[slot][qs][0];
    }
#pragma unroll
    for (int tt = 0; tt < 4; tt++) {
      int row = 16 * tt + m_;
      int cs = (g * 4 + q) ^ (row & 7);
      short8_t bh = *(const short8_t*)&lws[0][row][cs][0];
      short8_t bl = *(const short8_t*)&lws[1][row][cs][0];
      acc[tt] = __builtin_amdgcn_mfma_f32_16x16x32_bf16(ah, bh, acc[tt], 0, 0, 0);
      acc[tt] = __builtin_amdgcn_mfma_f32_16x16x32_bf16(ah, bl, acc[tt], 0, 0, 0);
      acc[tt] = __builtin_amdgcn_mfma_f32_16x16x32_bf16(al, bh, acc[tt], 0, 0, 0);
    }
  }
#pragma unroll
  for (int tt = 0; tt < 4; tt++) {
    float bia = bias[16 * tt + m_];
#pragma unroll
    for (int reg = 0; reg < 4; reg++) {
      int node = n0b + w * 16 + q * 4 + reg;
      if (node < N) {
        float val = fmaxf(acc[tt][reg] + bia, 0.f);
        short hh = f2bf(val);
        h1h[(size_t)node * HID + 16 * tt + m_] = hh;
        h1l[(size_t)node * HID + 16 * tt + m_] = f2bf(val - bf2f(hh));
      }
    }
  }
}

// ====== layer-2 fused: barrier-phased LDS pipeline ======
__global__ __launch_bounds__(256) void l2fused_k(
    const short* __restrict__ h1h, const short* __restrict__ h1l,
    const int* __restrict__ offs, const int* __restrict__ icnt,
    const int* __restrict__ nbr, const int* __restrict__ csr,
    const short* __restrict__ wth, const short* __restrict__ wtl,
    const float* __restrict__ bias, const float* __restrict__ linW,
    const int* __restrict__ batch, float* __restrict__ gs, float* __restrict__ gc, int N) {
  __shared__ __align__(16) short lws[2][64][16][8];  // 32 KB
  __shared__ __align__(16) short gh_s[192][4][8];    // 12 KB
  __shared__ __align__(16) short gl_s[192][4][8];    // 12 KB
  __shared__ __align__(16) int4 mid_s[192];          //  3 KB
  __shared__ int mlen_s[192];
  __shared__ int mbeg_s[192];

  const int t = threadIdx.x;
  const int lane = t & 63, w = t >> 6;
  const int m_ = lane & 15, q = lane >> 4;
  const int n0b = blockIdx.x * 64;

  // ---- phase A ----
  int node_c = n0b + w * 16 + m_;
  if (node_c >= N) node_c = N - 1;
  short8_t ash[2], asl[2];
#pragma unroll
  for (int s_ = 0; s_ < 2; s_++) {
    ash[s_] = *(const short8_t*)&h1h[(size_t)node_c * HID + s_ * 32 + q * 8];
    asl[s_] = *(const short8_t*)&h1l[(size_t)node_c * HID + s_ * 32 + q * 8];
  }
#pragma unroll
  for (int i = 0; i < 8; i++) {
    int chi = t + 256 * i;
    int plane = chi >> 10;
    int rem = chi & 1023;
    int row = rem >> 4, c = rem & 15;
    int g = c >> 2, qq = c & 3;
    const short* srcp = plane ? wtl : wth;
    short8_t wv = *(const short8_t*)&srcp[(size_t)row * 256 + g * 64 + 0 * 32 + qq * 8];
    *(short8_t*)&lws[plane][row][c ^ (row & 7)][0] = wv;
  }
  if (t < 192) {
    int r = t >> 6, nl = t & 63;
    int n_ = n0b + nl;
    if (n_ >= N) n_ = N - 1;
    int idx = r * N + n_;
    mid_s[t] = *(const int4*)&nbr[(size_t)idx * 4];
    mlen_s[t] = icnt[idx];
    mbeg_s[t] = offs[idx];
  }
  __syncthreads();

  f32x4 acc[4];
#pragma unroll
  for (int i = 0; i < 4; i++) acc[i] = (f32x4){0.f, 0.f, 0.f, 0.f};

#pragma unroll
  for (int s_ = 0; s_ < 2; s_++) {
    // ---- phase S(s_) ----
    if (s_ == 1) {
#pragma unroll
      for (int i = 0; i < 8; i++) {
        int chi = t + 256 * i;
        int plane = chi >> 10;
        int rem = chi & 1023;
        int row = rem >> 4, c = rem & 15;
        int g = c >> 2, qq = c & 3;
        const short* srcp = plane ? wtl : wth;
        short8_t wv = *(const short8_t*)&srcp[(size_t)row * 256 + g * 64 + 32 + qq * 8];
        *(short8_t*)&lws[plane][row][c ^ (row & 7)][0] = wv;
      }
    }
    int tslot[3], tq[3], tlen[3], tbeg[3];
    int4 tid4[3];
#pragma unroll
    for (int k = 0; k < 3; k++) {
      int tau = t + 256 * k;
      tslot[k] = tau >> 2;
      tq[k] = tau & 3;
      tid4[k] = mid_s[tslot[k]];
      tlen[k] = mlen_s[tslot[k]];
      tbeg[k] = mbeg_s[tslot[k]];
    }
    short8_t v0[3], v1[3], v2[3], v3[3];
#pragma unroll
    for (int k = 0; k < 3; k++) {
      int nself = n0b + (tslot[k] & 63);
      if (nself >= N) nself = N - 1;
      int g0 = (0 < tlen[k]) ? tid4[k].x : nself;
      int g1 = (1 < tlen[k]) ? tid4[k].y : nself;
      int g2 = (2 < tlen[k]) ? tid4[k].z : nself;
      int g3 = (3 < tlen[k]) ? tid4[k].w : nself;
      size_t co = (size_t)s_ * 32 + tq[k] * 8;
      v0[k] = *(const short8_t*)&h1h[(size_t)g0 * HID + co];
      v1[k] = *(const short8_t*)&h1h[(size_t)g1 * HID + co];
      v2[k] = *(const short8_t*)&h1h[(size_t)g2 * HID + co];
      v3[k] = *(const short8_t*)&h1h[(size_t)g3 * HID + co];
    }
#pragma unroll
    for (int k = 0; k < 3; k++) {
      float a[8];
      float k0 = (0 < tlen[k]) ? 1.f : 0.f;
      float k1 = (1 < tlen[k]) ? 1.f : 0.f;
      float k2 = (2 < tlen[k]) ? 1.f : 0.f;
      float k3 = (3 < tlen[k]) ? 1.f : 0.f;
#pragma unroll
      for (int i = 0; i < 8; i++)
        a[i] = k0 * bf2f(v0[k][i]) + k1 * bf2f(v1[k][i]) + k2 * bf2f(v2[k][i]) +
               k3 * bf2f(v3[k][i]);
      // rare tail: overflow CSR holds slots j>=4 at offs[idx] + (j-4)
      for (int j = 4; j < tlen[k]; j++) {
        short8_t u = *(const short8_t*)&h1h[(size_t)csr[tbeg[k] + j - 4] * HID + s_ * 32 +
                                            tq[k] * 8];
#pragma unroll
        for (int i = 0; i < 8; i++) a[i] += bf2f(u[i]);
      }
      float inv = 1.f / fmaxf((float)tlen[k], 1.f);
#pragma unroll
      for (int i = 0; i < 8; i++) a[i] *= inv;
      short8_t hi, lo;
      split8(a, &hi, &lo);
      int qs = tq[k] ^ (tslot[k] & 3);
      *(short8_t*)&gh_s[tslot[k]][qs][0] = hi;
      *(short8_t*)&gl_s[tslot[k]][qs][0] = lo;
    }
    __syncthreads();

    // ---- phase C(s_) ----
#pragma unroll
    for (int g = 0; g < 4; g++) {
      short8_t ah, al;
      if (g == 0) {
        ah = ash[s_];
        al = asl[s_];
      } else {
        int slot = (g - 1) * 64 + w * 16 + m_;
        int qs = q ^ (slot & 3);
        ah = *(const short8_t*)&gh_s[slot][qs][0];
        al = *(const short8_t*)&gl_s[slot][qs][0];
      }
#pragma unroll
      for (int tt = 0; tt < 4; tt++) {
        int row = 16 * tt + m_;
        int cs = (g * 4 + q) ^ (row & 7);
        short8_t bh = *(const short8_t*)&lws[0][row][cs][0];
        short8_t bl = *(const short8_t*)&lws[1][row][cs][0];
        acc[tt] = __builtin_amdgcn_mfma_f32_16x16x32_bf16(ah, bh, acc[tt], 0, 0, 0);
        acc[tt] = __builtin_amdgcn_mfma_f32_16x16x32_bf16(ah, bl, acc[tt], 0, 0, 0);
        acc[tt] = __builtin_amdgcn_mfma_f32_16x16x32_bf16(al, bh, acc[tt], 0, 0, 0);
      }
    }
    if (s_ == 0) __syncthreads();
  }

  // ---- pooled epilogue ----
  float bia[4], lw0[4], lw1[4];
#pragma unroll
  for (int tt = 0; tt < 4; tt++) {
    int col = 16 * tt + m_;
    bia[tt] = bias[col];
    lw0[tt] = linW[col * 2 + 0];
    lw1[tt] = linW[col * 2 + 1];
  }
#pragma unroll
  for (int reg = 0; reg < 4; reg++) {
    int node = n0b + w * 16 + q * 4 + reg;
    float p0 = 0.f, p1 = 0.f;
#pragma unroll
    for (int tt = 0; tt < 4; tt++) {
      float v = fmaxf(acc[tt][reg] + bia[tt], 0.f);
      p0 += v * lw0[tt];
      p1 += v * lw1[tt];
    }
#pragma unroll
    for (int o = 1; o < 16; o <<= 1) {
      p0 += __shfl_xor(p0, o, 64);
      p1 += __shfl_xor(p1, o, 64);
    }
    if (m_ == 0 && node < N) {
      int g = batch[node];
      atomicAdd(&gs[g * 2 + 0], p0);
      atomicAdd(&gs[g * 2 + 1], p1);
      atomicAdd(&gc[g], 1.0f);
    }
  }
}

__global__ __launch_bounds__(256) void final_k(const float* __restrict__ gs,
                                               const float* __restrict__ gc,
                                               const float* __restrict__ linb,
                                               float* __restrict__ out, int G) {
  int i = blockIdx.x * 256 + threadIdx.x;
  if (i >= G * 2) return;
  int g = i >> 1, o = i & 1;
  out[i] = gs[i] / fmaxf(gc[g], 1.0f) + linb[o];
}

extern "C" void kernel_launch(void* const* d_in, const int* in_sizes, int n_in,
                              void* d_out, int out_size, void* d_ws, size_t ws_size,
                              hipStream_t stream) {
  const int* sid = (const int*)d_in[0];
  const int* cid = (const int*)d_in[1];
  const int* pid = (const int*)d_in[2];
  const int* ei = (const int*)d_in[3];
  const int* et = (const int*)d_in[4];
  const int* batch = (const int*)d_in[5];
  const float* se = (const float*)d_in[7];
  const float* ce = (const float*)d_in[8];
  const float* pe = (const float*)d_in[9];
  const float* W1 = (const float*)d_in[10];
  const float* root1 = (const float*)d_in[11];
  const float* b1 = (const float*)d_in[12];
  const float* W2 = (const float*)d_in[13];
  const float* root2 = (const float*)d_in[14];
  const float* b2 = (const float*)d_in[15];
  const float* linW = (const float*)d_in[16];
  const float* linb = (const float*)d_in[17];
  float* out = (float*)d_out;

  const int N = in_sizes[0];
  const int E = in_sizes[4];
  const int G = out_size / 2;
  const int* src = ei;
  const int* dst = ei + E;
  const int M = N * NREL;
  const int P = (M + 1023) / 1024;

  // ---- workspace layout (16B-aligned; icnt+cursor2+ovfn adjacent for one memset) ----
  char* w = (char*)d_ws;
  short* h1h = (short*)w;   w += (size_t)N * HID * sizeof(short);
  short* h1l = (short*)w;   w += (size_t)N * HID * sizeof(short);
  short* xh = (short*)w;    w += (size_t)N * EMB * sizeof(short);
  short* xl = (short*)w;    w += (size_t)N * EMB * sizeof(short);
  float* gs = (float*)w;    w += (size_t)G * 2 * sizeof(float);
  float* gc = (float*)w;    w += (size_t)G * sizeof(float);
  int* icnt = (int*)w;      w += (size_t)M * sizeof(int);
  int* cursor2 = (int*)w;   w += (size_t)M * sizeof(int);   // overflow-placement cursor
  int* ovfn = (int*)w;      w += 4 * sizeof(int);           // overflow count (16B block)
  int* offs = (int*)w;      w += (size_t)M * sizeof(int);
  int* nbr = (int*)w;       w += (size_t)M * 4 * sizeof(int);  // first-4 table
  int* csr = (int*)w;       w += (size_t)E * sizeof(int);      // overflow slots (j>=4)
  int* ovf_idx = (int*)w;   w += (size_t)E * sizeof(int);      // compact overflow list
  int* ovf_src = (int*)w;   w += (size_t)E * sizeof(int);
  short* w1h = (short*)w;   w += (size_t)64 * 128 * sizeof(short);
  short* w1l = (short*)w;   w += (size_t)64 * 128 * sizeof(short);
  short* w2h = (short*)w;   w += (size_t)64 * 256 * sizeof(short);
  short* w2l = (short*)w;   w += (size_t)64 * 256 * sizeof(short);
  int* psum = (int*)w;      w += (size_t)P * sizeof(int);
  if ((size_t)(w - (char*)d_ws) > ws_size) return;  // fail loudly, no OOB

  hipMemsetAsync(icnt, 0, ((size_t)2 * M + 4) * sizeof(int), stream);  // icnt+cursor2+ovfn
  hipMemsetAsync(gs, 0, (size_t)G * 3 * sizeof(float), stream);

  int prep_n = N * 8;  // covers E (1.5M) and weight ranges too for this problem size
  if (prep_n < E) prep_n = E;
  if (prep_n < 64 * 256) prep_n = 64 * 256;
  prep_k<<<(prep_n + 255) / 256, 256, 0, stream>>>(sid, cid, pid, se, ce, pe, xh, xl, src,
                                                   dst, et, icnt, nbr, ovf_idx, ovf_src, ovfn,
                                                   root1, W1, root2, W2, w1h, w1l, w2h, w2l,
                                                   N, E);
  scan1_k<<<P, 256, 0, stream>>>(icnt, psum, M);
  scan2_k<<<1, 256, 0, stream>>>(psum, P);
  scan3_k<<<P, 256, 0, stream>>>(icnt, psum, offs, M);
  ovfscatter_k<<<512, 256, 0, stream>>>(ovf_idx, ovf_src, ovfn, offs, cursor2, csr);

  int blocks = (N + 63) / 64;
  l1fused_k<<<blocks, 256, 0, stream>>>(xh, xl, offs, icnt, nbr, csr, w1h, w1l, b1, h1h, h1l,
                                        N);
  l2fused_k<<<blocks, 256, 0, stream>>>(h1h, h1l, offs, icnt, nbr, csr, w2h, w2l, b2, linW,
                                        batch, gs, gc, N);
  final_k<<<(G * 2 + 255) / 256, 256, 0, stream>>>(gs, gc, linb, out, G);
}

// Round 10
// 468.336 us; speedup vs baseline: 1.0831x; 1.0831x over previous
//
#include <hip/hip_runtime.h>
#include <hip/hip_bf16.h>

#define NREL 3
#define EMB 32
#define HID 64

typedef __attribute__((ext_vector_type(8))) short short8_t;
typedef __attribute__((ext_vector_type(4))) short short4_t;
typedef __attribute__((ext_vector_type(4))) float f32x4;

__device__ inline short f2bf(float v) {
  __hip_bfloat16 b = __float2bfloat16(v);
  short s;
  __builtin_memcpy(&s, &b, 2);
  return s;
}
__device__ inline float bf2f(short s) {
  __hip_bfloat16 b;
  __builtin_memcpy(&b, &s, 2);
  return __bfloat162float(b);
}
__device__ inline void split8(const float* v, short8_t* h, short8_t* l) {
#pragma unroll
  for (int i = 0; i < 8; i++) {
    short hh = f2bf(v[i]);
    (*h)[i] = hh;
    (*l)[i] = f2bf(v[i] - bf2f(hh));
  }
}

// ---- fused prep: embedding (hi/lo planes) + edge histogram + weight prep ----
__global__ __launch_bounds__(256) void prep_k(
    const int* __restrict__ sid, const int* __restrict__ cid, const int* __restrict__ pid,
    const float* __restrict__ se, const float* __restrict__ ce, const float* __restrict__ pe,
    short* __restrict__ xh, short* __restrict__ xl,
    const int* __restrict__ dst, const int* __restrict__ et, int* __restrict__ icnt,
    const float* __restrict__ root1, const float* __restrict__ W1,
    const float* __restrict__ root2, const float* __restrict__ W2,
    short* __restrict__ w1h, short* __restrict__ w1l,
    short* __restrict__ w2h, short* __restrict__ w2l, int N, int E) {
  int i = blockIdx.x * 256 + threadIdx.x;
  if (i < N * 8) {  // embedding: one float4 slice per thread
    int n = i >> 3, cg = i & 7;
    const float4 a = *(const float4*)&se[sid[n] * EMB + cg * 4];
    const float4 b = *(const float4*)&ce[cid[n] * EMB + cg * 4];
    const float4 c = *(const float4*)&pe[pid[n] * EMB + cg * 4];
    float v[4];
    v[0] = a.x + b.x + c.x; v[1] = a.y + b.y + c.y;
    v[2] = a.z + b.z + c.z; v[3] = a.w + b.w + c.w;
    short4_t h, l;
#pragma unroll
    for (int j = 0; j < 4; j++) {
      short hh = f2bf(v[j]);
      h[j] = hh;
      l[j] = f2bf(v[j] - bf2f(hh));
    }
    *(short4_t*)&xh[(size_t)n * EMB + cg * 4] = h;
    *(short4_t*)&xl[(size_t)n * EMB + cg * 4] = l;
  }
  if (i < E) atomicAdd(&icnt[et[i] * N + dst[i]], 1);
  if (i < 64 * 128) {  // layer-1 weights
    int k = i >> 6, n = i & 63;
    float v = (k < EMB) ? root1[k * 64 + n] : W1[(k - EMB) * 64 + n];
    short h = f2bf(v);
    w1h[n * 128 + k] = h;
    w1l[n * 128 + k] = f2bf(v - bf2f(h));
  }
  if (i < 64 * 256) {  // layer-2 weights
    int k = i >> 6, n = i & 63;
    float v = (k < HID) ? root2[k * 64 + n] : W2[(k - HID) * 64 + n];
    short h = f2bf(v);
    w2h[n * 256 + k] = h;
    w2l[n * 256 + k] = f2bf(v - bf2f(h));
  }
}

__global__ __launch_bounds__(256) void scan1_k(const int* __restrict__ icnt,
                                               int* __restrict__ psum, int M) {
  int base = blockIdx.x * 1024 + threadIdx.x * 4;
  int s = 0;
#pragma unroll
  for (int j = 0; j < 4; j++) {
    int i = base + j;
    if (i < M) s += icnt[i];
  }
  __shared__ int tmp[256];
  tmp[threadIdx.x] = s;
  __syncthreads();
  for (int off = 128; off > 0; off >>= 1) {
    if (threadIdx.x < off) tmp[threadIdx.x] += tmp[threadIdx.x + off];
    __syncthreads();
  }
  if (threadIdx.x == 0) psum[blockIdx.x] = tmp[0];
}

__global__ __launch_bounds__(256) void scan2_k(int* __restrict__ psum, int P) {
  __shared__ int tmp[256];
  __shared__ int carry_s;
  if (threadIdx.x == 0) carry_s = 0;
  __syncthreads();
  for (int base = 0; base < P; base += 256) {
    int i = base + threadIdx.x;
    int v = (i < P) ? psum[i] : 0;
    tmp[threadIdx.x] = v;
    __syncthreads();
    for (int off = 1; off < 256; off <<= 1) {
      int u = (threadIdx.x >= off) ? tmp[threadIdx.x - off] : 0;
      __syncthreads();
      tmp[threadIdx.x] += u;
      __syncthreads();
    }
    int carry = carry_s;
    if (i < P) psum[i] = carry + tmp[threadIdx.x] - v;
    __syncthreads();
    if (threadIdx.x == 0) carry_s = carry + tmp[255];
    __syncthreads();
  }
}

__global__ __launch_bounds__(256) void scan3_k(const int* __restrict__ icnt,
                                               const int* __restrict__ psum,
                                               int* __restrict__ offs, int M) {
  int base = blockIdx.x * 1024 + threadIdx.x * 4;
  int v[4];
  int s = 0;
#pragma unroll
  for (int j = 0; j < 4; j++) {
    int i = base + j;
    v[j] = (i < M) ? icnt[i] : 0;
    s += v[j];
  }
  __shared__ int tmp[256];
  tmp[threadIdx.x] = s;
  __syncthreads();
  for (int off = 1; off < 256; off <<= 1) {
    int u = (threadIdx.x >= off) ? tmp[threadIdx.x - off] : 0;
    __syncthreads();
    tmp[threadIdx.x] += u;
    __syncthreads();
  }
  int run = psum[blockIdx.x] + tmp[threadIdx.x] - s;
#pragma unroll
  for (int j = 0; j < 4; j++) {
    int i = base + j;
    if (i < M) {
      offs[i] = run;
      run += v[j];
    }
  }
}

// scatter: first 4 neighbors per (rel,node) into fixed-stride nbr table;
// overflow (j>=4) goes into csr at offs[idx]+j (rare: ~1.5% of edges).
__global__ __launch_bounds__(256) void scatter_k(const int* __restrict__ src,
                                                 const int* __restrict__ dst,
                                                 const int* __restrict__ et,
                                                 const int* __restrict__ offs,
                                                 int* __restrict__ cursor,
                                                 int* __restrict__ nbr,
                                                 int* __restrict__ csr, int E, int N) {
  int e = blockIdx.x * 256 + threadIdx.x;
  if (e >= E) return;
  int idx = et[e] * N + dst[e];
  int j = atomicAdd(&cursor[idx], 1);  // cursor zero-initialized
  int s = src[e];
  if (j < 4) nbr[(size_t)idx * 4 + j] = s;
  else csr[offs[idx] + j] = s;
}

// ====== layer-1 fused: phased LDS pipeline, single-plane weight staging (45.5 KB) ======
// A: w1h+meta -> LDS, self -> regs; S: gather; Ca: hi MFMAs; St: w1l; Cb: lo MFMAs.
__global__ __launch_bounds__(256) void l1fused_k(
    const short* __restrict__ xh, const short* __restrict__ xl,
    const int* __restrict__ offs, const int* __restrict__ icnt,
    const int* __restrict__ nbr, const int* __restrict__ csr,
    const short* __restrict__ wth, const short* __restrict__ wtl,
    const float* __restrict__ bias, short* __restrict__ h1h, short* __restrict__ h1l, int N) {
  __shared__ __align__(16) short lws[64][16][8];   // 16 KB (one plane)
  __shared__ __align__(16) short gh_s[192][4][8];  // 12 KB
  __shared__ __align__(16) short gl_s[192][4][8];  // 12 KB
  __shared__ __align__(16) int4 mid_s[192];        //  3 KB
  __shared__ int mlen_s[192];
  __shared__ int mbeg_s[192];

  const int t = threadIdx.x;
  const int lane = t & 63, w = t >> 6;
  const int m_ = lane & 15, q = lane >> 4;
  const int n0b = blockIdx.x * 64;

  // ---- phase A: hi-plane weights + meta -> LDS, self -> regs ----
  int node_c = n0b + w * 16 + m_;
  if (node_c >= N) node_c = N - 1;
  short8_t ah0 = *(const short8_t*)&xh[(size_t)node_c * EMB + q * 8];
  short8_t al0 = *(const short8_t*)&xl[(size_t)node_c * EMB + q * 8];
#pragma unroll
  for (int i = 0; i < 4; i++) {  // 1024 chunks / 256 threads
    int chi = t + 256 * i;
    int row = chi >> 4, c = chi & 15;
    short8_t wv = *(const short8_t*)&wth[(size_t)row * 128 + c * 8];
    *(short8_t*)&lws[row][c ^ (row & 7)][0] = wv;
  }
  if (t < 192) {
    int r = t >> 6, nl = t & 63;
    int n_ = n0b + nl;
    if (n_ >= N) n_ = N - 1;
    int idx = r * N + n_;
    mid_s[t] = *(const int4*)&nbr[(size_t)idx * 4];
    mlen_s[t] = icnt[idx];
    mbeg_s[t] = offs[idx];
  }
  __syncthreads();

  // ---- phase S: copy-shaped gather stage, 3 tasks/thread ----
  {
    int tslot[3], tq[3], tlen[3], tbeg[3];
    int4 tid4[3];
#pragma unroll
    for (int k = 0; k < 3; k++) {
      int tau = t + 256 * k;
      tslot[k] = tau >> 2;
      tq[k] = tau & 3;
      tid4[k] = mid_s[tslot[k]];
      tlen[k] = mlen_s[tslot[k]];
      tbeg[k] = mbeg_s[tslot[k]];
    }
    short8_t v0[3], v1[3], v2[3], v3[3];
#pragma unroll
    for (int k = 0; k < 3; k++) {
      int nself = n0b + (tslot[k] & 63);
      if (nself >= N) nself = N - 1;
      int g0 = (0 < tlen[k]) ? tid4[k].x : nself;
      int g1 = (1 < tlen[k]) ? tid4[k].y : nself;
      int g2 = (2 < tlen[k]) ? tid4[k].z : nself;
      int g3 = (3 < tlen[k]) ? tid4[k].w : nself;
      size_t co = (size_t)tq[k] * 8;
      v0[k] = *(const short8_t*)&xh[(size_t)g0 * EMB + co];
      v1[k] = *(const short8_t*)&xh[(size_t)g1 * EMB + co];
      v2[k] = *(const short8_t*)&xh[(size_t)g2 * EMB + co];
      v3[k] = *(const short8_t*)&xh[(size_t)g3 * EMB + co];
    }
#pragma unroll
    for (int k = 0; k < 3; k++) {
      float a[8];
      float k0 = (0 < tlen[k]) ? 1.f : 0.f;
      float k1 = (1 < tlen[k]) ? 1.f : 0.f;
      float k2 = (2 < tlen[k]) ? 1.f : 0.f;
      float k3 = (3 < tlen[k]) ? 1.f : 0.f;
#pragma unroll
      for (int i = 0; i < 8; i++)
        a[i] = k0 * bf2f(v0[k][i]) + k1 * bf2f(v1[k][i]) + k2 * bf2f(v2[k][i]) +
               k3 * bf2f(v3[k][i]);
      // rare tail (len > 4): overflow lives in csr at beg+j
      for (int j = 4; j < tlen[k]; j++) {
        short8_t u = *(const short8_t*)&xh[(size_t)csr[tbeg[k] + j] * EMB + tq[k] * 8];
#pragma unroll
        for (int i = 0; i < 8; i++) a[i] += bf2f(u[i]);
      }
      float inv = 1.f / fmaxf((float)tlen[k], 1.f);
#pragma unroll
      for (int i = 0; i < 8; i++) a[i] *= inv;
      short8_t hi, lo;
      split8(a, &hi, &lo);
      int qs = tq[k] ^ (tslot[k] & 3);
      *(short8_t*)&gh_s[tslot[k]][qs][0] = hi;
      *(short8_t*)&gl_s[tslot[k]][qs][0] = lo;
    }
  }
  __syncthreads();

  // ---- phase Ca: hi-plane MFMAs; latch a-fragments in regs ----
  f32x4 acc[4];
#pragma unroll
  for (int i = 0; i < 4; i++) acc[i] = (f32x4){0.f, 0.f, 0.f, 0.f};
  short8_t ahv[4], alv[4];
#pragma unroll
  for (int g = 0; g < 4; g++) {
    if (g == 0) {
      ahv[0] = ah0;
      alv[0] = al0;
    } else {
      int slot = (g - 1) * 64 + w * 16 + m_;
      int qs = q ^ (slot & 3);
      ahv[g] = *(const short8_t*)&gh_s[slot][qs][0];
      alv[g] = *(const short8_t*)&gl_s[slot][qs][0];
    }
#pragma unroll
    for (int tt = 0; tt < 4; tt++) {
      int row = 16 * tt + m_;
      int cs = (g * 4 + q) ^ (row & 7);
      short8_t bh = *(const short8_t*)&lws[row][cs][0];
      acc[tt] = __builtin_amdgcn_mfma_f32_16x16x32_bf16(ahv[g], bh, acc[tt], 0, 0, 0);
      acc[tt] = __builtin_amdgcn_mfma_f32_16x16x32_bf16(alv[g], bh, acc[tt], 0, 0, 0);
    }
  }
  __syncthreads();

  // ---- phase St: stage lo-plane weights ----
#pragma unroll
  for (int i = 0; i < 4; i++) {
    int chi = t + 256 * i;
    int row = chi >> 4, c = chi & 15;
    short8_t wv = *(const short8_t*)&wtl[(size_t)row * 128 + c * 8];
    *(short8_t*)&lws[row][c ^ (row & 7)][0] = wv;
  }
  __syncthreads();

  // ---- phase Cb: lo-plane MFMAs ----
#pragma unroll
  for (int g = 0; g < 4; g++) {
#pragma unroll
    for (int tt = 0; tt < 4; tt++) {
      int row = 16 * tt + m_;
      int cs = (g * 4 + q) ^ (row & 7);
      short8_t bl = *(const short8_t*)&lws[row][cs][0];
      acc[tt] = __builtin_amdgcn_mfma_f32_16x16x32_bf16(ahv[g], bl, acc[tt], 0, 0, 0);
    }
  }
  // epilogue: bias + relu + hi/lo split store
#pragma unroll
  for (int tt = 0; tt < 4; tt++) {
    float bia = bias[16 * tt + m_];
#pragma unroll
    for (int reg = 0; reg < 4; reg++) {
      int node = n0b + w * 16 + q * 4 + reg;
      if (node < N) {
        float val = fmaxf(acc[tt][reg] + bia, 0.f);
        short hh = f2bf(val);
        h1h[(size_t)node * HID + 16 * tt + m_] = hh;
        h1l[(size_t)node * HID + 16 * tt + m_] = f2bf(val - bf2f(hh));
      }
    }
  }
}

// ====== layer-2 fused: phased LDS pipeline, single-plane weight staging (45.5 KB) ======
__global__ __launch_bounds__(256) void l2fused_k(
    const short* __restrict__ h1h, const short* __restrict__ h1l,
    const int* __restrict__ offs, const int* __restrict__ icnt,
    const int* __restrict__ nbr, const int* __restrict__ csr,
    const short* __restrict__ wth, const short* __restrict__ wtl,
    const float* __restrict__ bias, const float* __restrict__ linW,
    const int* __restrict__ batch, float* __restrict__ gs, float* __restrict__ gc, int N) {
  __shared__ __align__(16) short lws[64][16][8];   // 16 KB (one plane, one K-half)
  __shared__ __align__(16) short gh_s[192][4][8];  // 12 KB
  __shared__ __align__(16) short gl_s[192][4][8];  // 12 KB
  __shared__ __align__(16) int4 mid_s[192];        //  3 KB
  __shared__ int mlen_s[192];
  __shared__ int mbeg_s[192];

  const int t = threadIdx.x;
  const int lane = t & 63, w = t >> 6;
  const int m_ = lane & 15, q = lane >> 4;
  const int n0b = blockIdx.x * 64;

  // ---- phase A: self -> regs; hi-weights(s0) + meta -> LDS ----
  int node_c = n0b + w * 16 + m_;
  if (node_c >= N) node_c = N - 1;
  short8_t ash[2], asl[2];
#pragma unroll
  for (int s_ = 0; s_ < 2; s_++) {
    ash[s_] = *(const short8_t*)&h1h[(size_t)node_c * HID + s_ * 32 + q * 8];
    asl[s_] = *(const short8_t*)&h1l[(size_t)node_c * HID + s_ * 32 + q * 8];
  }
#pragma unroll
  for (int i = 0; i < 4; i++) {  // hi plane, K-half 0
    int chi = t + 256 * i;
    int row = chi >> 4, c = chi & 15;
    int g = c >> 2, qq = c & 3;
    short8_t wv = *(const short8_t*)&wth[(size_t)row * 256 + g * 64 + 0 * 32 + qq * 8];
    *(short8_t*)&lws[row][c ^ (row & 7)][0] = wv;
  }
  if (t < 192) {
    int r = t >> 6, nl = t & 63;
    int n_ = n0b + nl;
    if (n_ >= N) n_ = N - 1;
    int idx = r * N + n_;
    mid_s[t] = *(const int4*)&nbr[(size_t)idx * 4];
    mlen_s[t] = icnt[idx];
    mbeg_s[t] = offs[idx];
  }
  __syncthreads();

  f32x4 acc[4];
#pragma unroll
  for (int i = 0; i < 4; i++) acc[i] = (f32x4){0.f, 0.f, 0.f, 0.f};

#pragma unroll
  for (int s_ = 0; s_ < 2; s_++) {
    // ---- phase S(s_): gather; on s_=1 also re-stage hi-weights(s1) ----
    if (s_ == 1) {
#pragma unroll
      for (int i = 0; i < 4; i++) {
        int chi = t + 256 * i;
        int row = chi >> 4, c = chi & 15;
        int g = c >> 2, qq = c & 3;
        short8_t wv = *(const short8_t*)&wth[(size_t)row * 256 + g * 64 + 32 + qq * 8];
        *(short8_t*)&lws[row][c ^ (row & 7)][0] = wv;
      }
    }
    int tslot[3], tq[3], tlen[3], tbeg[3];
    int4 tid4[3];
#pragma unroll
    for (int k = 0; k < 3; k++) {
      int tau = t + 256 * k;
      tslot[k] = tau >> 2;
      tq[k] = tau & 3;
      tid4[k] = mid_s[tslot[k]];
      tlen[k] = mlen_s[tslot[k]];
      tbeg[k] = mbeg_s[tslot[k]];
    }
    short8_t v0[3], v1[3], v2[3], v3[3];
#pragma unroll
    for (int k = 0; k < 3; k++) {
      int nself = n0b + (tslot[k] & 63);
      if (nself >= N) nself = N - 1;
      int g0 = (0 < tlen[k]) ? tid4[k].x : nself;
      int g1 = (1 < tlen[k]) ? tid4[k].y : nself;
      int g2 = (2 < tlen[k]) ? tid4[k].z : nself;
      int g3 = (3 < tlen[k]) ? tid4[k].w : nself;
      size_t co = (size_t)s_ * 32 + tq[k] * 8;
      v0[k] = *(const short8_t*)&h1h[(size_t)g0 * HID + co];
      v1[k] = *(const short8_t*)&h1h[(size_t)g1 * HID + co];
      v2[k] = *(const short8_t*)&h1h[(size_t)g2 * HID + co];
      v3[k] = *(const short8_t*)&h1h[(size_t)g3 * HID + co];
    }
#pragma unroll
    for (int k = 0; k < 3; k++) {
      float a[8];
      float k0 = (0 < tlen[k]) ? 1.f : 0.f;
      float k1 = (1 < tlen[k]) ? 1.f : 0.f;
      float k2 = (2 < tlen[k]) ? 1.f : 0.f;
      float k3 = (3 < tlen[k]) ? 1.f : 0.f;
#pragma unroll
      for (int i = 0; i < 8; i++)
        a[i] = k0 * bf2f(v0[k][i]) + k1 * bf2f(v1[k][i]) + k2 * bf2f(v2[k][i]) +
               k3 * bf2f(v3[k][i]);
      // rare tail (len > 4): overflow lives in csr at beg+j
      for (int j = 4; j < tlen[k]; j++) {
        short8_t u =
            *(const short8_t*)&h1h[(size_t)csr[tbeg[k] + j] * HID + s_ * 32 + tq[k] * 8];
#pragma unroll
        for (int i = 0; i < 8; i++) a[i] += bf2f(u[i]);
      }
      float inv = 1.f / fmaxf((float)tlen[k], 1.f);
#pragma unroll
      for (int i = 0; i < 8; i++) a[i] *= inv;
      short8_t hi, lo;
      split8(a, &hi, &lo);
      int qs = tq[k] ^ (tslot[k] & 3);
      *(short8_t*)&gh_s[tslot[k]][qs][0] = hi;
      *(short8_t*)&gl_s[tslot[k]][qs][0] = lo;
    }
    __syncthreads();

    // ---- phase Ca(s_): hi-plane MFMAs; latch a-fragments ----
    short8_t ahv[4], alv[4];
#pragma unroll
    for (int g = 0; g < 4; g++) {
      if (g == 0) {
        ahv[0] = ash[s_];
        alv[0] = asl[s_];
      } else {
        int slot = (g - 1) * 64 + w * 16 + m_;
        int qs = q ^ (slot & 3);
        ahv[g] = *(const short8_t*)&gh_s[slot][qs][0];
        alv[g] = *(const short8_t*)&gl_s[slot][qs][0];
      }
#pragma unroll
      for (int tt = 0; tt < 4; tt++) {
        int row = 16 * tt + m_;
        int cs = (g * 4 + q) ^ (row & 7);
        short8_t bh = *(const short8_t*)&lws[row][cs][0];
        acc[tt] = __builtin_amdgcn_mfma_f32_16x16x32_bf16(ahv[g], bh, acc[tt], 0, 0, 0);
        acc[tt] = __builtin_amdgcn_mfma_f32_16x16x32_bf16(alv[g], bh, acc[tt], 0, 0, 0);
      }
    }
    __syncthreads();

    // ---- phase St(s_): stage lo-plane weights for this K-half ----
#pragma unroll
    for (int i = 0; i < 4; i++) {
      int chi = t + 256 * i;
      int row = chi >> 4, c = chi & 15;
      int g = c >> 2, qq = c & 3;
      short8_t wv = *(const short8_t*)&wtl[(size_t)row * 256 + g * 64 + s_ * 32 + qq * 8];
      *(short8_t*)&lws[row][c ^ (row & 7)][0] = wv;
    }
    __syncthreads();

    // ---- phase Cb(s_): lo-plane MFMAs (a-fragments from regs) ----
#pragma unroll
    for (int g = 0; g < 4; g++) {
#pragma unroll
      for (int tt = 0; tt < 4; tt++) {
        int row = 16 * tt + m_;
        int cs = (g * 4 + q) ^ (row & 7);
        short8_t bl = *(const short8_t*)&lws[row][cs][0];
        acc[tt] = __builtin_amdgcn_mfma_f32_16x16x32_bf16(ahv[g], bl, acc[tt], 0, 0, 0);
      }
    }
    if (s_ == 0) __syncthreads();  // protect gh/gl + lws before S1 overwrites
  }

  // ---- pooled epilogue ----
  float bia[4], lw0[4], lw1[4];
#pragma unroll
  for (int tt = 0; tt < 4; tt++) {
    int col = 16 * tt + m_;
    bia[tt] = bias[col];
    lw0[tt] = linW[col * 2 + 0];
    lw1[tt] = linW[col * 2 + 1];
  }
#pragma unroll
  for (int reg = 0; reg < 4; reg++) {
    int node = n0b + w * 16 + q * 4 + reg;
    float p0 = 0.f, p1 = 0.f;
#pragma unroll
    for (int tt = 0; tt < 4; tt++) {
      float v = fmaxf(acc[tt][reg] + bia[tt], 0.f);
      p0 += v * lw0[tt];
      p1 += v * lw1[tt];
    }
#pragma unroll
    for (int o = 1; o < 16; o <<= 1) {
      p0 += __shfl_xor(p0, o, 64);
      p1 += __shfl_xor(p1, o, 64);
    }
    if (m_ == 0 && node < N) {
      int g = batch[node];
      atomicAdd(&gs[g * 2 + 0], p0);
      atomicAdd(&gs[g * 2 + 1], p1);
      atomicAdd(&gc[g], 1.0f);
    }
  }
}

__global__ __launch_bounds__(256) void final_k(const float* __restrict__ gs,
                                               const float* __restrict__ gc,
                                               const float* __restrict__ linb,
                                               float* __restrict__ out, int G) {
  int i = blockIdx.x * 256 + threadIdx.x;
  if (i >= G * 2) return;
  int g = i >> 1, o = i & 1;
  out[i] = gs[i] / fmaxf(gc[g], 1.0f) + linb[o];
}

extern "C" void kernel_launch(void* const* d_in, const int* in_sizes, int n_in,
                              void* d_out, int out_size, void* d_ws, size_t ws_size,
                              hipStream_t stream) {
  const int* sid = (const int*)d_in[0];
  const int* cid = (const int*)d_in[1];
  const int* pid = (const int*)d_in[2];
  const int* ei = (const int*)d_in[3];
  const int* et = (const int*)d_in[4];
  const int* batch = (const int*)d_in[5];
  const float* se = (const float*)d_in[7];
  const float* ce = (const float*)d_in[8];
  const float* pe = (const float*)d_in[9];
  const float* W1 = (const float*)d_in[10];
  const float* root1 = (const float*)d_in[11];
  const float* b1 = (const float*)d_in[12];
  const float* W2 = (const float*)d_in[13];
  const float* root2 = (const float*)d_in[14];
  const float* b2 = (const float*)d_in[15];
  const float* linW = (const float*)d_in[16];
  const float* linb = (const float*)d_in[17];
  float* out = (float*)d_out;

  const int N = in_sizes[0];
  const int E = in_sizes[4];
  const int G = out_size / 2;
  const int* src = ei;
  const int* dst = ei + E;
  const int M = N * NREL;
  const int P = (M + 1023) / 1024;

  // ---- workspace layout (16B-aligned blocks; icnt+cursor adjacent for one memset) ----
  char* w = (char*)d_ws;
  short* h1h = (short*)w;  w += (size_t)N * HID * sizeof(short);
  short* h1l = (short*)w;  w += (size_t)N * HID * sizeof(short);
  short* xh = (short*)w;   w += (size_t)N * EMB * sizeof(short);
  short* xl = (short*)w;   w += (size_t)N * EMB * sizeof(short);
  float* gs = (float*)w;   w += (size_t)G * 2 * sizeof(float);
  float* gc = (float*)w;   w += (size_t)G * sizeof(float);
  int* icnt = (int*)w;     w += (size_t)M * sizeof(int);
  int* cursor = (int*)w;   w += (size_t)M * sizeof(int);   // adjacent to icnt (joint memset)
  int* offs = (int*)w;     w += (size_t)M * sizeof(int);
  int* nbr = (int*)w;      w += (size_t)M * 4 * sizeof(int);  // first-4 table, fixed stride
  int* csr = (int*)w;      w += (size_t)E * sizeof(int);      // overflow slots only (j>=4)
  short* w1h = (short*)w;  w += (size_t)64 * 128 * sizeof(short);
  short* w1l = (short*)w;  w += (size_t)64 * 128 * sizeof(short);
  short* w2h = (short*)w;  w += (size_t)64 * 256 * sizeof(short);
  short* w2l = (short*)w;  w += (size_t)64 * 256 * sizeof(short);
  int* psum = (int*)w;     w += (size_t)P * sizeof(int);
  if ((size_t)(w - (char*)d_ws) > ws_size) return;  // fail loudly, no OOB

  hipMemsetAsync(icnt, 0, (size_t)2 * M * sizeof(int), stream);  // icnt + cursor
  hipMemsetAsync(gs, 0, (size_t)G * 3 * sizeof(float), stream);

  int prep_n = N * 8;  // covers E (1.5M) and weight ranges too for this problem size
  if (prep_n < E) prep_n = E;
  if (prep_n < 64 * 256) prep_n = 64 * 256;
  prep_k<<<(prep_n + 255) / 256, 256, 0, stream>>>(sid, cid, pid, se, ce, pe, xh, xl, dst, et,
                                                   icnt, root1, W1, root2, W2, w1h, w1l, w2h,
                                                   w2l, N, E);
  scan1_k<<<P, 256, 0, stream>>>(icnt, psum, M);
  scan2_k<<<1, 256, 0, stream>>>(psum, P);
  scan3_k<<<P, 256, 0, stream>>>(icnt, psum, offs, M);
  scatter_k<<<(E + 255) / 256, 256, 0, stream>>>(src, dst, et, offs, cursor, nbr, csr, E, N);

  int blocks = (N + 63) / 64;
  l1fused_k<<<blocks, 256, 0, stream>>>(xh, xl, offs, icnt, nbr, csr, w1h, w1l, b1, h1h, h1l,
                                        N);
  l2fused_k<<<blocks, 256, 0, stream>>>(h1h, h1l, offs, icnt, nbr, csr, w2h, w2l, b2, linW,
                                        batch, gs, gc, N);
  final_k<<<(G * 2 + 255) / 256, 256, 0, stream>>>(gs, gc, linb, out, G);
}